// Round 6
// baseline (641.527 us; speedup 1.0000x reference)
//
#include <hip/hip_runtime.h>
#include <stdint.h>

// Viterbi CRF decode: B=1024, T=1024, N=34 (32 tags + START=32 + END=33)
// One wave = one batch (1024 waves = 1024 SIMDs). Lane j<34 owns row j.
// Score vector is wave-uniform -> broadcast via 34 v_readlane into SGPRs
// (VALU pipe), NOT via LDS: the per-CU LDS pipe was the r4/r5 bottleneck
// (4 waves x 10 DS ops/step ~ 430 cyc/step/CU serialized). Adds are
// v_add_f32 vgpr,sgpr,vgpr. Eq-scan argmax fills the readlane->use gap.
// Backpointers packed 4 steps/word -> 1 ds_write_b32 per 4 steps.
#define BB 1024
#define TT 1024
#define NN 34
#define NEGV -6969.0f

__device__ __forceinline__ float rdlane_f(float v, int l) {
    return __int_as_float(__builtin_amdgcn_readlane(__float_as_int(v), l));
}
__device__ __forceinline__ float M3(float a, float b, float c) {
    return fmaxf(fmaxf(a, b), c);   // folds to v_max3_f32
}

__global__ __launch_bounds__(64, 1) void viterbi_wave(
        const float* __restrict__ feat,   // [B,T,34]
        const float* __restrict__ trans,  // [34,34]
        float* __restrict__ out)          // best[B] ++ path[B,T+1]
{
    __shared__ unsigned int bp32[256 * NN];        // packed bp, 34816 B
    __shared__ unsigned char Fm[16 * NN];          // chunk maps

    const int lane = threadIdx.x;
    const int bg   = blockIdx.x;
    const int jc   = (lane < NN) ? lane : (NN - 1);

    // transition row (constant over t) in VGPRs
    float tr[NN];
#pragma unroll
    for (int k = 0; k < NN; ++k) tr[k] = trans[jc * NN + k];
    const float trE = trans[33 * NN + jc];

    const float* fpp = feat + (size_t)bg * TT * NN + jc;
    float fr0 = fpp[0 * NN], fr1 = fpp[1 * NN], fr2 = fpp[2 * NN], fr3 = fpp[3 * NN];

    // wave-uniform score vector (readlane-produced -> SGPRs)
    float sk[NN];
#pragma unroll
    for (int k = 0; k < NN; ++k) sk[k] = (k == 32) ? 0.0f : NEGV;

    float m = NEGV;   // lane j's current score

    auto vstep = [&](float f) -> int {
        // exact reference fp order: (s[k] + f[j]) + tr[j][k]
        float vv[NN];
#pragma unroll
        for (int k = 0; k < NN; ++k) vv[k] = (sk[k] + f) + tr[k];

        // 34-leaf exact max: 11 triples + leftover, then 4 triples, then 2
        float t0  = M3(vv[0],  vv[1],  vv[2]);
        float t1  = M3(vv[3],  vv[4],  vv[5]);
        float t2  = M3(vv[6],  vv[7],  vv[8]);
        float t3  = M3(vv[9],  vv[10], vv[11]);
        float t4  = M3(vv[12], vv[13], vv[14]);
        float t5  = M3(vv[15], vv[16], vv[17]);
        float t6  = M3(vv[18], vv[19], vv[20]);
        float t7  = M3(vv[21], vv[22], vv[23]);
        float t8  = M3(vv[24], vv[25], vv[26]);
        float t9  = M3(vv[27], vv[28], vv[29]);
        float t10 = M3(vv[30], vv[31], vv[32]);
        float u0 = M3(t0, t1, t2);
        float u1 = M3(t3, t4, t5);
        float u2 = M3(t6, t7, t8);
        float u3 = M3(t9, t10, vv[33]);
        float mx = fmaxf(fmaxf(u0, u1), fmaxf(u2, u3));

        // broadcast NOW via readlane (VALU, no LDS); consumers are next
        // step's adds — the eq-scan below fills the SGPR-hazard gap
#pragma unroll
        for (int k = 0; k < NN; ++k) sk[k] = rdlane_f(mx, k);

        // argmax = first k attaining mx: 4 descending cmp/sel chains + min
        int am0 = 255, am1 = 255, am2 = 255, am3 = 255;
#pragma unroll
        for (int k = 33; k >= 0; --k) {
            bool e = (vv[k] == mx);
            if ((k & 3) == 0) am0 = e ? k : am0;
            else if ((k & 3) == 1) am1 = e ? k : am1;
            else if ((k & 3) == 2) am2 = e ? k : am2;
            else am3 = e ? k : am3;
        }
        m = mx;
        return min(min(am0, am1), min(am2, am3));
    };

    int wofs = lane;   // bp32 word index for this lane's group writes
    for (int n = 0; n < 255; ++n) {
        int a0, a1, a2, a3;
        { float f = fr0; fr0 = fpp[4 * NN]; a0 = vstep(f); }
        { float f = fr1; fr1 = fpp[5 * NN]; a1 = vstep(f); }
        { float f = fr2; fr2 = fpp[6 * NN]; a2 = vstep(f); }
        { float f = fr3; fr3 = fpp[7 * NN]; a3 = vstep(f); }
        unsigned u = (unsigned)a0 | ((unsigned)a1 << 8) |
                     ((unsigned)a2 << 16) | ((unsigned)a3 << 24);
        if (lane < NN) bp32[wofs] = u;
        wofs += NN;
        fpp += 4 * NN;
    }
    {   // epilogue group (t = 1020..1023)
        int a0 = vstep(fr0), a1 = vstep(fr1), a2 = vstep(fr2), a3 = vstep(fr3);
        unsigned u = (unsigned)a0 | ((unsigned)a1 << 8) |
                     ((unsigned)a2 << 16) | ((unsigned)a3 << 24);
        if (lane < NN) bp32[wofs] = u;
    }

    // ---- end transition + final max/argmax (uniform across lanes)
    float fs = m + trE;
    float bm = rdlane_f(fs, 0);
    int bi = 0;
#pragma unroll
    for (int k = 1; k < NN; ++k) {
        float v = rdlane_f(fs, k);
        bool g = (v > bm);                 // strict > => first index on ties
        bm = g ? v : bm;
        bi = g ? k : bi;
    }
    if (lane == 0) out[bg] = bm;

    // ---- backtrack on LDS (single wave: ds ops are wave-ordered)
    // byte(t, s) at (t>>2)*136 + s*4 + (t&3); chunk c spans 2176 B
    const unsigned char* bpb = (const unsigned char*)bp32;

    // level-1: 16 chunks x 34 hypotheses = 544 jobs; 9 jobs/lane
    int cc[9], xx[9], mm[9], cb[9];
#pragma unroll
    for (int r = 0; r < 9; ++r) {
        int job = 64 * r + lane;
        if (job > 543) job = 543;
        cc[r] = job / 34;
        xx[r] = job - 34 * cc[r];
        mm[r] = xx[r];
        cb[r] = cc[r] * 2176;
    }
    for (int i = 63; i >= 0; --i) {
        int ioff = ((i >> 2) * 136) + (i & 3);
#pragma unroll
        for (int r = 0; r < 9; ++r) mm[r] = bpb[cb[r] + ioff + 4 * mm[r]];
    }
#pragma unroll
    for (int r = 0; r < 9; ++r) Fm[cc[r] * NN + xx[r]] = (unsigned char)mm[r];

    // level-2: serial 16-chunk scan (uniform)
    int e = bi;
    int myeb = (lane == 15) ? e : 0;
#pragma unroll
    for (int c2 = 15; c2 >= 1; --c2) {
        e = Fm[c2 * NN + e];
        myeb = (lane == c2 - 1) ? e : myeb;
    }

    // emit: lanes 0..15 re-chase their chunk and write the path
    float* po = out + BB + (size_t)bg * (TT + 1);
    if (lane < 16) {
        int mm2 = myeb;
        int base = lane * 2176;
        for (int i = 63; i >= 0; --i) {
            mm2 = bpb[base + ((i >> 2) * 136) + (i & 3) + 4 * mm2];
            po[lane * 64 + i] = (float)mm2;
        }
    }
    if (lane == 16) po[TT] = (float)bi;
}

extern "C" void kernel_launch(void* const* d_in, const int* in_sizes, int n_in,
                              void* d_out, int out_size, void* d_ws, size_t ws_size,
                              hipStream_t stream) {
    const float* feat  = (const float*)d_in[0];   // [1024,1024,34]
    const float* trans = (const float*)d_in[1];   // [34,34]
    float* out = (float*)d_out;                   // 1024 + 1024*1025 floats
    (void)d_ws; (void)ws_size;

    viterbi_wave<<<BB, 64, 0, stream>>>(feat, trans, out);
}